// Round 1
// baseline (150.719 us; speedup 1.0000x reference)
//
#include <hip/hip_runtime.h>

#define T 8
#define C 512
#define HW 196
#define NSEG 16                 // n
#define B_TOT (NSEG * HW)       // 3136
#define NH 4
#define KK 5
#define NO 20                   // NH*KK
#define S_SPLIT 2               // c split for k_logits
#define C_HALF (C / S_SPLIT)    // 256

// ---------------------------------------------------------------------------
// Kernel A1: partial logits over half the channels.
// grid (2, 8, 16) = (c-half s, t, n); 196 threads, lane = hw (coalesced).
// W reads are wave-uniform -> scalar s_load path (no VALU/LDS cost).
// ---------------------------------------------------------------------------
__global__ __launch_bounds__(256) void k_logits(const float* __restrict__ x,
                                                const float* __restrict__ W,
                                                float* __restrict__ pl) {
    const int hw = threadIdx.x;        // 0..195
    const int s  = blockIdx.x;         // 0..1
    const int t  = blockIdx.y;         // 0..7
    const int n  = blockIdx.z;         // 0..15
    const int cbase = s * C_HALF;

    const float* xp = x + ((size_t)((n * T + t) * C) + cbase) * HW + hw;

    float acc[NO];
#pragma unroll
    for (int o = 0; o < NO; ++o) acc[o] = 0.f;

    float xv[8], xn[8];
#pragma unroll
    for (int u = 0; u < 8; ++u) xv[u] = xp[u * HW];

    for (int c0 = 0; c0 < C_HALF; c0 += 8) {
        if (c0 + 8 < C_HALF) {
#pragma unroll
            for (int u = 0; u < 8; ++u) xn[u] = xp[(c0 + 8 + u) * HW];
        }
        const float* wr = W + cbase + c0;   // uniform base
#pragma unroll
        for (int o = 0; o < NO; ++o) {
#pragma unroll
            for (int u = 0; u < 8; ++u)
                acc[o] = fmaf(xv[u], wr[o * C + u], acc[o]);  // wr idx uniform
        }
#pragma unroll
        for (int u = 0; u < 8; ++u) xv[u] = xn[u];
    }

    const int b = n * HW + hw;
    float* pp = pl + ((size_t)((s * T + t) * NO)) * B_TOT + b;
#pragma unroll
    for (int o = 0; o < NO; ++o) pp[o * B_TOT] = acc[o];
}

// ---------------------------------------------------------------------------
// Kernel A2: reduce the 2 partials, softmax per head over 5 taps,
// store weights as (T, H, K, B) so k_conv reads coalesced over b.
// ---------------------------------------------------------------------------
__global__ __launch_bounds__(256) void k_softmax(const float* __restrict__ pl,
                                                 float* __restrict__ wgt) {
    const int b = blockIdx.x * 256 + threadIdx.x;
    const int t = blockIdx.y;
    if (b >= B_TOT) return;

    float lg[NO];
#pragma unroll
    for (int o = 0; o < NO; ++o)
        lg[o] = pl[((size_t)((0 * T + t) * NO + o)) * B_TOT + b] +
                pl[((size_t)((1 * T + t) * NO + o)) * B_TOT + b];

#pragma unroll
    for (int h = 0; h < NH; ++h) {
        float m = lg[h * KK];
#pragma unroll
        for (int k = 1; k < KK; ++k) m = fmaxf(m, lg[h * KK + k]);
        float e[KK];
        float sum = 0.f;
#pragma unroll
        for (int k = 0; k < KK; ++k) {
            e[k] = __expf(lg[h * KK + k] - m);
            sum += e[k];
        }
        const float r = 1.f / sum;
#pragma unroll
        for (int k = 0; k < KK; ++k)
            wgt[((size_t)((t * NH + h) * KK + k)) * B_TOT + b] = e[k] * r;
    }
}

// ---------------------------------------------------------------------------
// Kernel B: causal dynamic conv. grid (64 channel-octs, 16 n); 196 threads,
// lane = hw. Weights loaded once per 8 channels (same head), x and out
// accessed in coalesced rows.
// ---------------------------------------------------------------------------
__global__ __launch_bounds__(256) void k_conv(const float* __restrict__ x,
                                              const float* __restrict__ wgt,
                                              float* __restrict__ out) {
    const int hw = threadIdx.x;    // 0..195
    const int cg = blockIdx.x;     // 0..63
    const int n  = blockIdx.y;     // 0..15
    const int c0 = cg * 8;
    const int h  = c0 >> 7;        // head; an oct never straddles heads
    const int b  = n * HW + hw;

    float w[T][KK];
#pragma unroll
    for (int t = 0; t < T; ++t)
#pragma unroll
        for (int k = 0; k < KK; ++k)
            w[t][k] = wgt[((size_t)((t * NH + h) * KK + k)) * B_TOT + b];

#pragma unroll 1
    for (int ci = 0; ci < 8; ++ci) {
        const int c = c0 + ci;
        const float* xp = x + ((size_t)(n * T * C + c)) * HW + hw;
        float xv[T];
#pragma unroll
        for (int t = 0; t < T; ++t) xv[t] = xp[(size_t)t * C * HW];

        float* op = out + ((size_t)(n * T * C + c)) * HW + hw;
#pragma unroll
        for (int t = 0; t < T; ++t) {
            float acc = 0.f;
#pragma unroll
            for (int k = 0; k < KK; ++k) {
                const int j = t + k - 4;   // causal window, zero-padded left
                if (j >= 0) acc = fmaf(w[t][k], xv[j], acc);
            }
            op[(size_t)t * C * HW] = acc;
        }
    }
}

// ---------------------------------------------------------------------------
extern "C" void kernel_launch(void* const* d_in, const int* in_sizes, int n_in,
                              void* d_out, int out_size, void* d_ws, size_t ws_size,
                              hipStream_t stream) {
    const float* x = (const float*)d_in[0];   // (128, 512, 14, 14)
    const float* W = (const float*)d_in[1];   // (20, 512)
    float* out = (float*)d_out;               // (128, 512, 14, 14)

    // workspace: partial logits (2*8*20*3136 fl = 4.0 MB) + weights (2.0 MB)
    float* pl  = (float*)d_ws;
    float* wgt = pl + (size_t)S_SPLIT * T * NO * B_TOT;

    k_logits<<<dim3(S_SPLIT, T, NSEG), 196, 0, stream>>>(x, W, pl);
    k_softmax<<<dim3((B_TOT + 255) / 256, T), 256, 0, stream>>>(pl, wgt);
    k_conv<<<dim3(C / 8, NSEG), 196, 0, stream>>>(x, wgt, out);
}

// Round 2
// 125.841 us; speedup vs baseline: 1.1977x; 1.1977x over previous
//
#include <hip/hip_runtime.h>

#define T 8
#define C 512
#define HW 196
#define NSEG 16                  // n
#define NT (NSEG * T)            // 128
#define B_TOT (NSEG * HW)        // 3136
#define NH 4
#define KK 5
#define NO 20                    // NH*KK
#define S_SPLIT 8                // c split for k_logits
#define CCH (C / S_SPLIT)        // 64 channels per chunk

// ---------------------------------------------------------------------------
// Kernel A1: partial logits over a 64-channel chunk.
// grid (98, 8): x = flattened (nt,hw)/256, y = channel chunk. 256 threads.
// 784 blocks -> ~3 blocks/CU, ~12 waves/CU; 8-deep load prefetch.
// W reads are wave-uniform -> scalar loads.
// ---------------------------------------------------------------------------
__global__ __launch_bounds__(256) void k_logits(const float* __restrict__ x,
                                                const float* __restrict__ W,
                                                float* __restrict__ pl) {
    const int idx = blockIdx.x * 256 + threadIdx.x;   // 0..25087
    const int nt  = idx / HW;
    const int hw  = idx - nt * HW;
    const int s   = blockIdx.y;
    const int cbase = s * CCH;

    const float* xp = x + ((size_t)nt * C + cbase) * HW + hw;

    float acc[NO];
#pragma unroll
    for (int o = 0; o < NO; ++o) acc[o] = 0.f;

    float xv[8], xn[8];
#pragma unroll
    for (int u = 0; u < 8; ++u) xv[u] = xp[u * HW];

#pragma unroll
    for (int c0 = 0; c0 < CCH; c0 += 8) {
        if (c0 + 8 < CCH) {
#pragma unroll
            for (int u = 0; u < 8; ++u) xn[u] = xp[(c0 + 8 + u) * HW];
        }
        const float* wr = W + cbase + c0;   // wave-uniform
#pragma unroll
        for (int o = 0; o < NO; ++o) {
#pragma unroll
            for (int u = 0; u < 8; ++u)
                acc[o] = fmaf(xv[u], wr[o * C + u], acc[o]);
        }
#pragma unroll
        for (int u = 0; u < 8; ++u) xv[u] = xn[u];
    }

    // pl layout: [s][nt][o][hw]
    float* pp = pl + ((size_t)(s * NT + nt) * NO) * HW + hw;
#pragma unroll
    for (int o = 0; o < NO; ++o) pp[o * HW] = acc[o];
}

// ---------------------------------------------------------------------------
// Kernel A2: reduce 8 partials, softmax over 5 taps for ONE head.
// grid (13, T, NH), 256 threads. Stores weights (T,H,K,B): coalesced over b.
// ---------------------------------------------------------------------------
__global__ __launch_bounds__(256) void k_softmax(const float* __restrict__ pl,
                                                 float* __restrict__ wgt) {
    const int b = blockIdx.x * 256 + threadIdx.x;
    const int t = blockIdx.y;
    const int h = blockIdx.z;
    if (b >= B_TOT) return;
    const int n  = b / HW;
    const int hw = b - n * HW;
    const int nt = n * T + t;

    float lg[KK];
#pragma unroll
    for (int k = 0; k < KK; ++k) {
        float sm = 0.f;
#pragma unroll
        for (int s = 0; s < S_SPLIT; ++s)
            sm += pl[((size_t)(s * NT + nt) * NO + h * KK + k) * HW + hw];
        lg[k] = sm;
    }

    float m = lg[0];
#pragma unroll
    for (int k = 1; k < KK; ++k) m = fmaxf(m, lg[k]);
    float e[KK];
    float sum = 0.f;
#pragma unroll
    for (int k = 0; k < KK; ++k) {
        e[k] = __expf(lg[k] - m);
        sum += e[k];
    }
    const float r = 1.f / sum;
#pragma unroll
    for (int k = 0; k < KK; ++k)
        wgt[((size_t)((t * NH + h) * KK + k)) * B_TOT + b] = e[k] * r;
}

// ---------------------------------------------------------------------------
// Kernel B: causal dynamic conv, fully flat: one thread per (n, c, hw).
// 6272 blocks of 256 -> ~24 blocks/CU; all 48 loads independent.
// ---------------------------------------------------------------------------
__global__ __launch_bounds__(256) void k_conv(const float* __restrict__ x,
                                              const float* __restrict__ wgt,
                                              float* __restrict__ out) {
    const int idx = blockIdx.x * 256 + threadIdx.x;  // < 16*512*196
    const int hw  = idx % HW;
    const int t1  = idx / HW;          // n*C + c
    const int c   = t1 % C;
    const int n   = t1 / C;
    const int h   = c >> 7;            // head
    const int b   = n * HW + hw;

    float w[T][KK];
#pragma unroll
    for (int t = 0; t < T; ++t)
#pragma unroll
        for (int k = 0; k < KK; ++k)
            w[t][k] = wgt[((size_t)((t * NH + h) * KK + k)) * B_TOT + b];

    const size_t base = ((size_t)(n * T) * C + c) * HW + hw;
    float xv[T];
#pragma unroll
    for (int t = 0; t < T; ++t) xv[t] = x[base + (size_t)t * C * HW];

#pragma unroll
    for (int t = 0; t < T; ++t) {
        float acc = 0.f;
#pragma unroll
        for (int k = 0; k < KK; ++k) {
            const int j = t + k - 4;   // causal, zero-padded left
            if (j >= 0) acc = fmaf(w[t][k], xv[j], acc);
        }
        out[base + (size_t)t * C * HW] = acc;
    }
}

// ---------------------------------------------------------------------------
extern "C" void kernel_launch(void* const* d_in, const int* in_sizes, int n_in,
                              void* d_out, int out_size, void* d_ws, size_t ws_size,
                              hipStream_t stream) {
    const float* x = (const float*)d_in[0];   // (128, 512, 14, 14)
    const float* W = (const float*)d_in[1];   // (20, 512)
    float* out = (float*)d_out;               // (128, 512, 14, 14)

    // workspace: partials 8*128*20*196 fl = 16.1 MB, weights 160*3136 fl = 2 MB
    float* pl  = (float*)d_ws;
    float* wgt = pl + (size_t)S_SPLIT * NT * NO * HW;

    k_logits<<<dim3(25088 / 256, S_SPLIT), 256, 0, stream>>>(x, W, pl);
    k_softmax<<<dim3((B_TOT + 255) / 256, T, NH), 256, 0, stream>>>(pl, wgt);
    k_conv<<<dim3((NSEG * C * HW) / 256), 256, 0, stream>>>(x, wgt, out);
}